// Round 5
// baseline (997.060 us; speedup 1.0000x reference)
//
#include <hip/hip_runtime.h>

// Encoder_8718783611479: stateless per-step LSTMCell => one GEMM + elementwise.
//   gates = xt @ W_ih^T (+ b_ih + b_hh), only i,g,o gates live (f * c_prev = 0)
//   out = sigmoid(sigmoid(o_g)*tanh(sigmoid(i_g)*tanh(g_g)))
// xt[b,t,k] = x[b*43200 + k*240 + t]  (K=180 strided, M=t contiguous)
//
// v6 = v5 with the occupancy arithmetic fixed. v5's __launch_bounds__(384,3)
// = 3 waves/SIMD = only 2 blocks/CU (12 waves, 37.5%) -- paid for keeping
// bfrag (72 VGPR) resident. But W reloads from the prepacked L2-hot pack are
// single coalesced 16B loads (cheap remat), so trade residency for TLP:
// (384,5) -> <=102 VGPR, 3 blocks/CU, 18 waves. W loaded inside the tile
// loop; under the tighter budget the allocator remats per tile (that's the
// intent). Everything else (one-shot staging, register 4x4 transpose, XOR
// swizzle, per-tile compact epilogue + realign s_barrier -- the proven
// write-compactness mechanism, WRITE_SIZE was exactly ideal) unchanged.

#define B_SZ 2048
#define T_SZ 240
#define K_SZ 180
#define H_SZ 90
#define KP   192   // K padded to 6*32
#define TB   80    // t per block
#define NP   3     // parts per batch
#define NTT  5     // 16-row t-tiles per block

#define WS_B_OFF 110592   // W frags [3][6][6][64]x16B, then [3][96] f32 biases

typedef __bf16 bf16x8 __attribute__((ext_vector_type(8)));
typedef __bf16 bf16x4 __attribute__((ext_vector_type(4)));
typedef float  f32x4  __attribute__((ext_vector_type(4)));

__device__ __forceinline__ float sigmoidf_(float x) {
    return __builtin_amdgcn_rcpf(1.0f + __expf(-x));
}
__device__ __forceinline__ float tanhf_(float x) {
    return 1.0f - 2.0f * __builtin_amdgcn_rcpf(__expf(2.0f * x) + 1.0f);
}

// Even XOR key per row t; granule = 4 bf16 = 8B. Swizzle within 16-granule
// (128B) groups. Even key preserves b128 granule-pair adjacency (so the
// fragment read is one aligned ds_read_b128). Measured conflicts: negligible.
__device__ __forceinline__ int skey(int t) {
    return (2 * (t + (t >> 4))) & 14;
}
__device__ __forceinline__ int sgran(int g, int t) {
    return (g & ~15) | ((g ^ skey(t)) & 15);
}

// ---------------- prepack: W fragments + fused bias into d_ws ----------------
__global__ __launch_bounds__(384) void prepack_kernel(
    const float* __restrict__ W_ih,
    const float* __restrict__ b_ih,
    const float* __restrict__ b_hh,
    void* __restrict__ ws)
{
    __bf16* wp = (__bf16*)ws;
    float*  bp = (float*)((char*)ws + WS_B_OFF);
    const int gb[3] = {0, 180, 270};   // i, g, o row bases in W_ih (4H=360 rows)

    const int bid = blockIdx.x;
    const int tid = threadIdx.x;
    if (bid < 18) {
        const int g  = bid / 6;
        const int ks = bid % 6;
        const int w  = tid >> 6;
        const int l  = tid & 63;
        const int q  = l >> 4;
        const int n  = l & 15;
        const int h  = w * 16 + n;
        bf16x8 f;
        #pragma unroll
        for (int j = 0; j < 8; ++j) {
            int k = ks * 32 + q * 8 + j;
            float v = (h < H_SZ && k < K_SZ) ? W_ih[(size_t)(gb[g] + h) * K_SZ + k] : 0.0f;
            f[j] = (__bf16)v;
        }
        // fragment order: [g][ks][wave][lane] x 16B -> coalesced load in main
        *(bf16x8*)(wp + (size_t)(((g * 6 + ks) * 6 + w) * 64 + l) * 8) = f;
    } else {
        if (tid < 288) {
            int g = tid / 96, hh = tid % 96;
            bp[g * 96 + hh] = (hh < H_SZ) ? (b_ih[gb[g] + hh] + b_hh[gb[g] + hh]) : 0.0f;
        }
    }
}

// ---------------- main kernel ----------------
__global__ __launch_bounds__(384, 5) void lstm_fused_kernel(
    const float* __restrict__ x,
    const void*  __restrict__ ws,
    float* __restrict__ out)
{
    __shared__ __align__(16) __bf16 aBuf[TB * KP];   // 30.7 KB, swizzled [t][k]

    const int bid  = blockIdx.x;
    const int b    = bid / NP;
    const int part = bid - b * NP;
    const int t0   = part * TB;

    const int tid  = threadIdx.x;
    const int wave = tid >> 6;      // 0..5 -> h-tile
    const int lane = tid & 63;
    const int q    = lane >> 4;     // quad 0..3
    const int n    = lane & 15;
    const int h    = wave * 16 + n; // output column; valid if < 90
    const bool hv  = (h < H_SZ);

    const float* xb = x + (size_t)b * (K_SZ * T_SZ) + t0;

    // zero-fill k-padding granules 45..47 of each row (swizzle is a per-row
    // bijection on slots, so zero slots never collide with data slots)
    if (tid < TB * 3) {
        int t  = tid / 3;
        int gz = 45 + (tid - (tid / 3) * 3);
        *(unsigned long long*)(aBuf + t * KP + sgran(gz, t) * 4) = 0ull;
    }

    // ---- one-shot staging: 900 4x4 blocks, register transpose, b64 writes ----
    #pragma unroll
    for (int p = 0; p < 3; ++p) {
        int u = tid + p * 384;
        if (p < 2 || u < 900) {                  // 45 k-granules x 20 t4
            int k4 = u / 20;
            int t4 = u - k4 * 20;
            const float* src = xb + (k4 * 4) * T_SZ + t4 * 4;
            f32x4 r0 = *(const f32x4*)(src);
            f32x4 r1 = *(const f32x4*)(src + T_SZ);
            f32x4 r2 = *(const f32x4*)(src + 2 * T_SZ);
            f32x4 r3 = *(const f32x4*)(src + 3 * T_SZ);
            #pragma unroll
            for (int j = 0; j < 4; ++j) {
                int t = t4 * 4 + j;
                bf16x4 w;
                w[0] = (__bf16)r0[j]; w[1] = (__bf16)r1[j];
                w[2] = (__bf16)r2[j]; w[3] = (__bf16)r3[j];
                *(bf16x4*)(aBuf + t * KP + sgran(k4, t) * 4) = w;
            }
        }
    }

    const bf16x8* wp = (const bf16x8*)ws;
    const float*  bp = (const float*)((const char*)ws + WS_B_OFF);
    const float bias_i = bp[0 * 96 + h];   // h <= 95, zero-padded
    const float bias_g = bp[1 * 96 + h];
    const float bias_o = bp[2 * 96 + h];
    float* ob = out + (size_t)b * (T_SZ * H_SZ) + (size_t)t0 * H_SZ;

    __syncthreads();   // staging complete

    // ---- tt-outer: per-tile MFMA + immediate compact epilogue ----
    #pragma unroll
    for (int tt = 0; tt < NTT; ++tt) {
        f32x4 acc0 = {0.f, 0.f, 0.f, 0.f};
        f32x4 acc1 = {0.f, 0.f, 0.f, 0.f};
        f32x4 acc2 = {0.f, 0.f, 0.f, 0.f};
        const int t = tt * 16 + n;
        #pragma unroll
        for (int ks = 0; ks < 6; ++ks) {
            // W fragments loaded per tile (coalesced 16B, L2-hot pack);
            // under the (384,5) VGPR budget the allocator streams these
            // instead of keeping 72 regs resident.
            bf16x8 b0 = wp[((0 * 6 + ks) * 6 + wave) * 64 + lane];
            bf16x8 b1 = wp[((1 * 6 + ks) * 6 + wave) * 64 + lane];
            bf16x8 b2 = wp[((2 * 6 + ks) * 6 + wave) * 64 + lane];
            int g = ks * 8 + 2 * q;            // even granule-pair base
            bf16x8 a = *(const bf16x8*)(aBuf + t * KP + sgran(g, t) * 4);
            acc0 = __builtin_amdgcn_mfma_f32_16x16x32_bf16(a, b0, acc0, 0, 0, 0);
            acc1 = __builtin_amdgcn_mfma_f32_16x16x32_bf16(a, b1, acc1, 0, 0, 0);
            acc2 = __builtin_amdgcn_mfma_f32_16x16x32_bf16(a, b2, acc2, 0, 0, 0);
        }
        // C/D layout: col = lane&15 -> h, row = q*4+e -> t within tile
        if (hv) {
            const int tg = tt * 16 + q * 4;
            #pragma unroll
            for (int e = 0; e < 4; ++e) {
                float gi = acc0[e] + bias_i;
                float gg = acc1[e] + bias_g;
                float go = acc2[e] + bias_o;
                float cc = sigmoidf_(gi) * tanhf_(gg);
                float hh = sigmoidf_(go) * tanhf_(cc);
                ob[(size_t)(tg + e) * H_SZ + h] = sigmoidf_(hh);
            }
        }
        // wave re-alignment only (no data dependency): keeps all 6 waves'
        // stores to each out line within one tile window -> single writeback
        if (tt + 1 < NTT) __builtin_amdgcn_s_barrier();
    }
}

extern "C" void kernel_launch(void* const* d_in, const int* in_sizes, int n_in,
                              void* d_out, int out_size, void* d_ws, size_t ws_size,
                              hipStream_t stream) {
    const float* x    = (const float*)d_in[0];
    const float* W_ih = (const float*)d_in[1];
    // d_in[2] = W_hh: dead (h0 = c0 = 0 at every timestep)
    const float* b_ih = (const float*)d_in[3];
    const float* b_hh = (const float*)d_in[4];
    float* out = (float*)d_out;

    // ~112 KB of workspace: prepacked W fragments + fused biases
    prepack_kernel<<<dim3(19), dim3(384), 0, stream>>>(W_ih, b_ih, b_hh, d_ws);
    lstm_fused_kernel<<<dim3(B_SZ * NP), dim3(384), 0, stream>>>(x, d_ws, out);
}

// Round 6
// 692.227 us; speedup vs baseline: 1.4404x; 1.4404x over previous
//
#include <hip/hip_runtime.h>

// Encoder_8718783611479: stateless per-step LSTMCell => one GEMM + elementwise.
//   gates = xt @ W_ih^T (+ b_ih + b_hh), only i,g,o gates live (f * c_prev = 0)
//   out = sigmoid(sigmoid(o_g)*tanh(sigmoid(i_g)*tanh(g_g)))
// xt[b,t,k] = x[b*43200 + k*240 + t]  (K=180 strided, M=t contiguous)
//
// v7 = v5 core (register-resident W @ 2 blocks/CU, one-shot swizzled LDS
// stage, per-tile compact epilogue + realign s_barrier) + cross-part
// pipelining. v6 proved W streaming is catastrophic (FETCH +560MB = W pack
// evicted from L2 under x streaming; WRITE re-amplified to 845MB from wave
// drift) -> W stays in registers. v5's residual gap vs the ~84us traffic
// floor is serial stage->compute phases (HBM idle during compute, cold
// staging stall per block x 12 rounds). Fix: persistent blocks (grid 512,
// 4 batches x 3 parts each), double-buffered aBuf, T14 async-stage split:
// issue part p+1 global loads into regs BEFORE part p compute, cvt+transpose+
// ds_write AFTER, one __syncthreads per part. HBM stays busy under compute;
// cold stall amortized 12x.

#define B_SZ 2048
#define T_SZ 240
#define K_SZ 180
#define H_SZ 90
#define KP   192   // K padded to 6*32
#define TB   80    // t per part
#define NTT  5     // 16-row t-tiles per part
#define BPB  4     // batches per block
#define NPARTS 12  // BPB * 3
#define NBLK 512   // B_SZ / BPB

#define WS_B_OFF 110592   // W frags [3][6][6][64]x16B, then [3][96] f32 biases

typedef __bf16 bf16x8 __attribute__((ext_vector_type(8)));
typedef __bf16 bf16x4 __attribute__((ext_vector_type(4)));
typedef float  f32x4  __attribute__((ext_vector_type(4)));

__device__ __forceinline__ float sigmoidf_(float x) {
    return __builtin_amdgcn_rcpf(1.0f + __expf(-x));
}
__device__ __forceinline__ float tanhf_(float x) {
    return 1.0f - 2.0f * __builtin_amdgcn_rcpf(__expf(2.0f * x) + 1.0f);
}

// Even XOR key per row t; granule = 4 bf16 = 8B. Swizzle within 16-granule
// (128B) groups. Even key preserves b128 granule-pair adjacency (so the
// fragment read is one aligned ds_read_b128). Measured conflicts: negligible.
__device__ __forceinline__ int skey(int t) {
    return (2 * (t + (t >> 4))) & 14;
}
__device__ __forceinline__ int sgran(int g, int t) {
    return (g & ~15) | ((g ^ skey(t)) & 15);
}

// ---------------- prepack: W fragments + fused bias into d_ws ----------------
__global__ __launch_bounds__(384) void prepack_kernel(
    const float* __restrict__ W_ih,
    const float* __restrict__ b_ih,
    const float* __restrict__ b_hh,
    void* __restrict__ ws)
{
    __bf16* wp = (__bf16*)ws;
    float*  bp = (float*)((char*)ws + WS_B_OFF);
    const int gb[3] = {0, 180, 270};   // i, g, o row bases in W_ih (4H=360 rows)

    const int bid = blockIdx.x;
    const int tid = threadIdx.x;
    if (bid < 18) {
        const int g  = bid / 6;
        const int ks = bid % 6;
        const int w  = tid >> 6;
        const int l  = tid & 63;
        const int q  = l >> 4;
        const int n  = l & 15;
        const int h  = w * 16 + n;
        bf16x8 f;
        #pragma unroll
        for (int j = 0; j < 8; ++j) {
            int k = ks * 32 + q * 8 + j;
            float v = (h < H_SZ && k < K_SZ) ? W_ih[(size_t)(gb[g] + h) * K_SZ + k] : 0.0f;
            f[j] = (__bf16)v;
        }
        // fragment order: [g][ks][wave][lane] x 16B -> coalesced load in main
        *(bf16x8*)(wp + (size_t)(((g * 6 + ks) * 6 + w) * 64 + l) * 8) = f;
    } else {
        if (tid < 288) {
            int g = tid / 96, hh = tid % 96;
            bp[g * 96 + hh] = (hh < H_SZ) ? (b_ih[gb[g] + hh] + b_hh[gb[g] + hh]) : 0.0f;
        }
    }
}

// ---------------- main kernel ----------------
__global__ __launch_bounds__(384, 3) void lstm_fused_kernel(
    const float* __restrict__ x,
    const void*  __restrict__ ws,
    float* __restrict__ out)
{
    __shared__ __align__(16) __bf16 aBuf[2][TB * KP];   // 2 x 30.7 KB, swizzled

    const int tid  = threadIdx.x;
    const int wave = tid >> 6;      // 0..5 -> h-tile
    const int lane = tid & 63;
    const int q    = lane >> 4;     // quad 0..3
    const int n    = lane & 15;
    const int h    = wave * 16 + n; // output column; valid if < 90
    const bool hv  = (h < H_SZ);

    // ---- W fragments: register-resident for the whole kernel (72 VGPR) ----
    const bf16x8* wp = (const bf16x8*)ws;
    bf16x8 bfrag[3][6];
    #pragma unroll
    for (int g = 0; g < 3; ++g)
        #pragma unroll
        for (int ks = 0; ks < 6; ++ks)
            bfrag[g][ks] = wp[((g * 6 + ks) * 6 + wave) * 64 + lane];

    const float* bp = (const float*)((const char*)ws + WS_B_OFF);
    const float bias_i = bp[0 * 96 + h];   // h <= 95, zero-padded
    const float bias_g = bp[1 * 96 + h];
    const float bias_o = bp[2 * 96 + h];

    // zero-fill k-padding granules 45..47 of every row, both buffers (once)
    if (tid < TB * 3) {
        int t  = tid / 3;
        int gz = 45 + (tid - (tid / 3) * 3);
        *(unsigned long long*)(aBuf[0] + t * KP + sgran(gz, t) * 4) = 0ull;
        *(unsigned long long*)(aBuf[1] + t * KP + sgran(gz, t) * 4) = 0ull;
    }

    // staging geometry: unit u -> (k4 = u/20, t4 = u%20); 900 units total
    const int k4a = tid / 20,           t4a = tid - (tid / 20) * 20;
    const int k4b = (tid + 384) / 20,   t4b = (tid + 384) - ((tid + 384) / 20) * 20;
    const int k4c = (tid + 768) / 20,   t4c = (tid + 768) - ((tid + 768) / 20) * 20;
    const bool u2v = (tid < 132);       // unit tid+768 < 900

    const int b0 = blockIdx.x * BPB;

#define LOADU(R, K4, T4, XB)                                            \
    {                                                                   \
        const float* src = (XB) + ((K4) * 4) * T_SZ + (T4) * 4;         \
        R[0] = *(const f32x4*)(src);                                    \
        R[1] = *(const f32x4*)(src + T_SZ);                             \
        R[2] = *(const f32x4*)(src + 2 * T_SZ);                         \
        R[3] = *(const f32x4*)(src + 3 * T_SZ);                         \
    }
#define WRITEU(DST, R, K4, T4)                                          \
    {                                                                   \
        _Pragma("unroll")                                               \
        for (int j = 0; j < 4; ++j) {                                   \
            int t = (T4) * 4 + j;                                       \
            bf16x4 w;                                                   \
            w[0] = (__bf16)R[0][j]; w[1] = (__bf16)R[1][j];             \
            w[2] = (__bf16)R[2][j]; w[3] = (__bf16)R[3][j];             \
            *(bf16x4*)((DST) + t * KP + sgran((K4), t) * 4) = w;        \
        }                                                               \
    }

    f32x4 r0[4], r1[4], r2[4];

    // ---- prologue: stage part 0 (batch b0, t0 = 0) into aBuf[0] ----
    {
        const float* xb = x + (size_t)b0 * (K_SZ * T_SZ);
        LOADU(r0, k4a, t4a, xb);
        LOADU(r1, k4b, t4b, xb);
        if (u2v) LOADU(r2, k4c, t4c, xb);
        WRITEU(aBuf[0], r0, k4a, t4a);
        WRITEU(aBuf[0], r1, k4b, t4b);
        if (u2v) WRITEU(aBuf[0], r2, k4c, t4c);
    }
    __syncthreads();

    int bb = b0, pp = 0;
    #pragma unroll 1
    for (int gp = 0; gp < NPARTS; ++gp) {
        const int cur = gp & 1;

        // ---- issue next part's global loads (in flight under compute) ----
        int bn = bb, pn = pp + 1;
        if (pn == 3) { pn = 0; ++bn; }
        if (gp + 1 < NPARTS) {
            const float* xb = x + (size_t)bn * (K_SZ * T_SZ) + pn * TB;
            LOADU(r0, k4a, t4a, xb);
            LOADU(r1, k4b, t4b, xb);
            if (u2v) LOADU(r2, k4c, t4c, xb);
        }

        // ---- compute part gp: tt-outer, per-tile compact epilogue ----
        const __bf16* ab = aBuf[cur];
        float* ob = out + (size_t)bb * (T_SZ * H_SZ) + (size_t)(pp * TB) * H_SZ;
        #pragma unroll
        for (int tt = 0; tt < NTT; ++tt) {
            f32x4 acc0 = {0.f, 0.f, 0.f, 0.f};
            f32x4 acc1 = {0.f, 0.f, 0.f, 0.f};
            f32x4 acc2 = {0.f, 0.f, 0.f, 0.f};
            const int t = tt * 16 + n;
            #pragma unroll
            for (int ks = 0; ks < 6; ++ks) {
                int g = ks * 8 + 2 * q;            // even granule-pair base
                bf16x8 a = *(const bf16x8*)(ab + t * KP + sgran(g, t) * 4);
                acc0 = __builtin_amdgcn_mfma_f32_16x16x32_bf16(a, bfrag[0][ks], acc0, 0, 0, 0);
                acc1 = __builtin_amdgcn_mfma_f32_16x16x32_bf16(a, bfrag[1][ks], acc1, 0, 0, 0);
                acc2 = __builtin_amdgcn_mfma_f32_16x16x32_bf16(a, bfrag[2][ks], acc2, 0, 0, 0);
            }
            // C/D layout: col = lane&15 -> h, row = q*4+e -> t within tile
            if (hv) {
                const int tg = tt * 16 + q * 4;
                #pragma unroll
                for (int e = 0; e < 4; ++e) {
                    float gi = acc0[e] + bias_i;
                    float gg = acc1[e] + bias_g;
                    float go = acc2[e] + bias_o;
                    float cc = sigmoidf_(gi) * tanhf_(gg);
                    float hh = sigmoidf_(go) * tanhf_(cc);
                    ob[(size_t)(tg + e) * H_SZ + h] = sigmoidf_(hh);
                }
            }
            // realign waves: keeps all 6 waves' stores to each out line
            // within one tile window -> single writeback (proven mechanism)
            if (tt + 1 < NTT) __builtin_amdgcn_s_barrier();
        }

        // ---- land the staged data into the other buffer ----
        if (gp + 1 < NPARTS) {
            __bf16* dst = aBuf[cur ^ 1];
            WRITEU(dst, r0, k4a, t4a);
            WRITEU(dst, r1, k4b, t4b);
            if (u2v) WRITEU(dst, r2, k4c, t4c);
        }
        __syncthreads();   // ds_writes visible; aBuf[cur] reads complete
        bb = bn; pp = pn;
    }

#undef LOADU
#undef WRITEU
}

extern "C" void kernel_launch(void* const* d_in, const int* in_sizes, int n_in,
                              void* d_out, int out_size, void* d_ws, size_t ws_size,
                              hipStream_t stream) {
    const float* x    = (const float*)d_in[0];
    const float* W_ih = (const float*)d_in[1];
    // d_in[2] = W_hh: dead (h0 = c0 = 0 at every timestep)
    const float* b_ih = (const float*)d_in[3];
    const float* b_hh = (const float*)d_in[4];
    float* out = (float*)d_out;

    // ~112 KB of workspace: prepacked W fragments + fused biases
    prepack_kernel<<<dim3(19), dim3(384), 0, stream>>>(W_ih, b_ih, b_hh, d_ws);
    lstm_fused_kernel<<<dim3(NBLK), dim3(384), 0, stream>>>(x, d_ws, out);
}

// Round 7
// 594.973 us; speedup vs baseline: 1.6758x; 1.1635x over previous
//
#include <hip/hip_runtime.h>

// Encoder_8718783611479: stateless per-step LSTMCell => one GEMM + elementwise.
//   gates = xt @ W_ih^T (+ b_ih + b_hh), only i,g,o gates live (f * c_prev = 0)
//   out = sigmoid(sigmoid(o_g)*tanh(sigmoid(i_g)*tanh(g_g)))
// xt[b,t,k] = x[b*43200 + k*240 + t]  (K=180 strided, M=t contiguous)
//
// v8 = v5 (best: ~190us kernel) + register-budget pin + staging-load hoist.
// Every failed version (v1/v2/v6/v7) shares one signature: allocator ignores
// the launch_bounds budget (VGPR 48-84), remats W or spills prefetch regs to
// scratch (v7: +55MB WRITE, +70MB FETCH of scratch traffic). Fix:
// amdgpu_waves_per_eu(3,3) pins min AND max -> allocator has no occupancy
// incentive, uses the 170-reg budget; bfrag[3][6] (72 VGPR) truly resident.
// Staging: all ~12 global 16B loads issued before any cvt/ds_write (explicit
// unrolled arrays, static indices) -> max MLP during the cold HBM stall.
// Proven v5 mechanisms untouched: grid 6144 (inter-block overlap), one-shot
// swizzled LDS stage, register 4x4 transpose, per-tile compact epilogue +
// realign s_barrier (WRITE_SIZE was exactly ideal 172.8MB).

#define B_SZ 2048
#define T_SZ 240
#define K_SZ 180
#define H_SZ 90
#define KP   192   // K padded to 6*32
#define TB   80    // t per block
#define NP   3     // parts per batch
#define NTT  5     // 16-row t-tiles per block

#define WS_B_OFF 110592   // W frags [3][6][6][64]x16B, then [3][96] f32 biases

typedef __bf16 bf16x8 __attribute__((ext_vector_type(8)));
typedef __bf16 bf16x4 __attribute__((ext_vector_type(4)));
typedef float  f32x4  __attribute__((ext_vector_type(4)));

__device__ __forceinline__ float sigmoidf_(float x) {
    return __builtin_amdgcn_rcpf(1.0f + __expf(-x));
}
__device__ __forceinline__ float tanhf_(float x) {
    return 1.0f - 2.0f * __builtin_amdgcn_rcpf(__expf(2.0f * x) + 1.0f);
}

// Even XOR key per row t; granule = 4 bf16 = 8B. Swizzle within 16-granule
// (128B) groups. Even key preserves b128 granule-pair adjacency (so the
// fragment read is one aligned ds_read_b128). Measured conflicts: negligible.
__device__ __forceinline__ int skey(int t) {
    return (2 * (t + (t >> 4))) & 14;
}
__device__ __forceinline__ int sgran(int g, int t) {
    return (g & ~15) | ((g ^ skey(t)) & 15);
}

// ---------------- prepack: W fragments + fused bias into d_ws ----------------
__global__ __launch_bounds__(384) void prepack_kernel(
    const float* __restrict__ W_ih,
    const float* __restrict__ b_ih,
    const float* __restrict__ b_hh,
    void* __restrict__ ws)
{
    __bf16* wp = (__bf16*)ws;
    float*  bp = (float*)((char*)ws + WS_B_OFF);
    const int gb[3] = {0, 180, 270};   // i, g, o row bases in W_ih (4H=360 rows)

    const int bid = blockIdx.x;
    const int tid = threadIdx.x;
    if (bid < 18) {
        const int g  = bid / 6;
        const int ks = bid % 6;
        const int w  = tid >> 6;
        const int l  = tid & 63;
        const int q  = l >> 4;
        const int n  = l & 15;
        const int h  = w * 16 + n;
        bf16x8 f;
        #pragma unroll
        for (int j = 0; j < 8; ++j) {
            int k = ks * 32 + q * 8 + j;
            float v = (h < H_SZ && k < K_SZ) ? W_ih[(size_t)(gb[g] + h) * K_SZ + k] : 0.0f;
            f[j] = (__bf16)v;
        }
        // fragment order: [g][ks][wave][lane] x 16B -> coalesced load in main
        *(bf16x8*)(wp + (size_t)(((g * 6 + ks) * 6 + w) * 64 + l) * 8) = f;
    } else {
        if (tid < 288) {
            int g = tid / 96, hh = tid % 96;
            bp[g * 96 + hh] = (hh < H_SZ) ? (b_ih[gb[g] + hh] + b_hh[gb[g] + hh]) : 0.0f;
        }
    }
}

// ---------------- main kernel ----------------
__global__ __launch_bounds__(384)
__attribute__((amdgpu_waves_per_eu(3, 3)))
void lstm_fused_kernel(
    const float* __restrict__ x,
    const void*  __restrict__ ws,
    float* __restrict__ out)
{
    __shared__ __align__(16) __bf16 aBuf[TB * KP];   // 30.7 KB, swizzled [t][k]

    const int bid  = blockIdx.x;
    const int b    = bid / NP;
    const int part = bid - b * NP;
    const int t0   = part * TB;

    const int tid  = threadIdx.x;
    const int wave = tid >> 6;      // 0..5 -> h-tile
    const int lane = tid & 63;
    const int q    = lane >> 4;     // quad 0..3
    const int n    = lane & 15;
    const int h    = wave * 16 + n; // output column; valid if < 90
    const bool hv  = (h < H_SZ);

    const float* xb = x + (size_t)b * (K_SZ * T_SZ) + t0;

    // staging geometry: unit u -> (k4 = u/20, t4 = u%20); 900 units total
    const int k4a = tid / 20,         t4a = tid - (tid / 20) * 20;
    const int k4b = (tid + 384) / 20, t4b = (tid + 384) - ((tid + 384) / 20) * 20;
    const int k4c = (tid + 768) / 20, t4c = (tid + 768) - ((tid + 768) / 20) * 20;
    const bool u2v = (tid < 132);     // unit tid+768 < 900

    // ---- issue ALL staging loads first (max memory-level parallelism) ----
    f32x4 r0[4], r1[4], r2[4];
    {
        const float* sa = xb + (k4a * 4) * T_SZ + t4a * 4;
        const float* sb = xb + (k4b * 4) * T_SZ + t4b * 4;
        const float* sc = xb + (k4c * 4) * T_SZ + t4c * 4;
        #pragma unroll
        for (int r = 0; r < 4; ++r) r0[r] = *(const f32x4*)(sa + r * T_SZ);
        #pragma unroll
        for (int r = 0; r < 4; ++r) r1[r] = *(const f32x4*)(sb + r * T_SZ);
        if (u2v) {
            #pragma unroll
            for (int r = 0; r < 4; ++r) r2[r] = *(const f32x4*)(sc + r * T_SZ);
        }
    }

    // ---- W fragments: register-resident (72 VGPR, under the pinned budget) ----
    const bf16x8* wp = (const bf16x8*)ws;
    bf16x8 bfrag[3][6];
    #pragma unroll
    for (int g = 0; g < 3; ++g)
        #pragma unroll
        for (int ks = 0; ks < 6; ++ks)
            bfrag[g][ks] = wp[((g * 6 + ks) * 6 + wave) * 64 + lane];

    const float* bp = (const float*)((const char*)ws + WS_B_OFF);
    const float bias_i = bp[0 * 96 + h];   // h <= 95, zero-padded
    const float bias_g = bp[1 * 96 + h];
    const float bias_o = bp[2 * 96 + h];
    float* ob = out + (size_t)b * (T_SZ * H_SZ) + (size_t)t0 * H_SZ;

    // zero-fill k-padding granules 45..47 (per-row bijection: no collisions)
    if (tid < TB * 3) {
        int t  = tid / 3;
        int gz = 45 + (tid - (tid / 3) * 3);
        *(unsigned long long*)(aBuf + t * KP + sgran(gz, t) * 4) = 0ull;
    }

    // ---- register 4x4 transpose + packed b64 LDS writes ----
#define WRITEU(R, K4, T4)                                               \
    {                                                                   \
        _Pragma("unroll")                                               \
        for (int j = 0; j < 4; ++j) {                                   \
            int t = (T4) * 4 + j;                                       \
            bf16x4 w;                                                   \
            w[0] = (__bf16)R[0][j]; w[1] = (__bf16)R[1][j];             \
            w[2] = (__bf16)R[2][j]; w[3] = (__bf16)R[3][j];             \
            *(bf16x4*)(aBuf + t * KP + sgran((K4), t) * 4) = w;         \
        }                                                               \
    }
    WRITEU(r0, k4a, t4a);
    WRITEU(r1, k4b, t4b);
    if (u2v) WRITEU(r2, k4c, t4c);
#undef WRITEU

    __syncthreads();   // staging complete

    // ---- tt-outer: per-tile MFMA + immediate compact epilogue ----
    #pragma unroll
    for (int tt = 0; tt < NTT; ++tt) {
        f32x4 acc0 = {0.f, 0.f, 0.f, 0.f};
        f32x4 acc1 = {0.f, 0.f, 0.f, 0.f};
        f32x4 acc2 = {0.f, 0.f, 0.f, 0.f};
        const int t = tt * 16 + n;
        #pragma unroll
        for (int ks = 0; ks < 6; ++ks) {
            int g = ks * 8 + 2 * q;            // even granule-pair base
            bf16x8 a = *(const bf16x8*)(aBuf + t * KP + sgran(g, t) * 4);
            acc0 = __builtin_amdgcn_mfma_f32_16x16x32_bf16(a, bfrag[0][ks], acc0, 0, 0, 0);
            acc1 = __builtin_amdgcn_mfma_f32_16x16x32_bf16(a, bfrag[1][ks], acc1, 0, 0, 0);
            acc2 = __builtin_amdgcn_mfma_f32_16x16x32_bf16(a, bfrag[2][ks], acc2, 0, 0, 0);
        }
        // C/D layout: col = lane&15 -> h, row = q*4+e -> t within tile
        if (hv) {
            const int tg = tt * 16 + q * 4;
            #pragma unroll
            for (int e = 0; e < 4; ++e) {
                float gi = acc0[e] + bias_i;
                float gg = acc1[e] + bias_g;
                float go = acc2[e] + bias_o;
                float cc = sigmoidf_(gi) * tanhf_(gg);
                float hh = sigmoidf_(go) * tanhf_(cc);
                ob[(size_t)(tg + e) * H_SZ + h] = sigmoidf_(hh);
            }
        }
        // wave re-alignment only (no data dependency): keeps all 6 waves'
        // stores to each out line within one tile window -> single writeback
        if (tt + 1 < NTT) __builtin_amdgcn_s_barrier();
    }
}

extern "C" void kernel_launch(void* const* d_in, const int* in_sizes, int n_in,
                              void* d_out, int out_size, void* d_ws, size_t ws_size,
                              hipStream_t stream) {
    const float* x    = (const float*)d_in[0];
    const float* W_ih = (const float*)d_in[1];
    // d_in[2] = W_hh: dead (h0 = c0 = 0 at every timestep)
    const float* b_ih = (const float*)d_in[3];
    const float* b_hh = (const float*)d_in[4];
    float* out = (float*)d_out;

    // ~112 KB of workspace: prepacked W fragments + fused biases
    prepack_kernel<<<dim3(19), dim3(384), 0, stream>>>(W_ih, b_ih, b_hh, d_ws);
    lstm_fused_kernel<<<dim3(B_SZ * NP), dim3(384), 0, stream>>>(x, d_ws, out);
}